// Round 1
// baseline (3595.700 us; speedup 1.0000x reference)
//
#include <hip/hip_runtime.h>
#include <hip/hip_bf16.h>
#include <stdint.h>

typedef unsigned short u16;
typedef unsigned int u32;

#define NFILE 50000
#define NCLASS 150000
#define NFUNC 300000
#define NTOT 500000
#define EDG 300000
#define NRELS 13
#define RTOT 2900000

typedef __attribute__((ext_vector_type(8))) short bf16x8;
typedef __attribute__((ext_vector_type(4))) float f32x4;

__device__ __forceinline__ u16 f2b(float v){
    u32 u = __float_as_uint(v);
    u += 0x7fffu + ((u >> 16) & 1u);
    return (u16)(u >> 16);
}
__device__ __forceinline__ float b2f(u16 b){
    return __uint_as_float(((u32)b) << 16);
}

struct EdgePtrs { const int* e[NRELS]; };
struct RelMeta  { int base[NRELS]; };

// ---------------- weight prep: transpose + bf16 + Wr/bias sums ----------------
__global__ void prep_weights(const float* __restrict__ Wl, const float* __restrict__ bl,
                             const float* __restrict__ Wr,
                             u16* __restrict__ WlT, u16* __restrict__ WrSumT,
                             float* __restrict__ blSum){
    int tid = blockIdx.x * 256 + threadIdx.x;
    if (tid >= 2 * 16384) return;
    int l   = tid >> 14;
    int rem = tid & 16383;
    int n   = rem >> 7;
    int k   = rem & 127;
    const int m[3][4] = {{0,1,0,0},{1,1,2,1},{1,2,2,2}};
    #pragma unroll
    for (int ci = 0; ci < 4; ++ci){
        float w = Wl[(((l*4)+ci)*128 + k)*128 + n];
        WlT[((l*4+ci)*128 + n)*128 + k] = f2b(w);
    }
    #pragma unroll
    for (int t = 0; t < 3; ++t){
        float s = 0.f;
        #pragma unroll
        for (int ci = 0; ci < 4; ++ci)
            s += (float)m[t][ci] * Wr[(((l*4)+ci)*128 + k)*128 + n];
        WrSumT[((l*3+t)*128 + n)*128 + k] = f2b(s);
    }
    if (k == 0){
        #pragma unroll
        for (int t = 0; t < 3; ++t){
            float s = 0.f;
            #pragma unroll
            for (int ci = 0; ci < 4; ++ci)
                s += (float)m[t][ci] * bl[(l*4+ci)*128 + n];
            blSum[(l*3+t)*128 + n] = s;
        }
    }
}

// ---------------- CSR build ----------------
__global__ void count_kernel(EdgePtrs ep, RelMeta rm, int* __restrict__ off){
    int rel = blockIdx.y;
    int e = blockIdx.x * 256 + threadIdx.x;
    if (e >= EDG) return;
    int dst = ep.e[rel][EDG + e];
    atomicAdd(&off[rm.base[rel] + dst], 1);
}

__global__ void scan1(int* __restrict__ data, int* __restrict__ bsums, int n){
    __shared__ int sd[256];
    int tid = threadIdx.x;
    long base = (long)blockIdx.x * 2048 + (long)tid * 8;
    int v[8]; int tot = 0;
    #pragma unroll
    for (int i = 0; i < 8; ++i){
        long ix = base + i;
        v[i] = (ix < n) ? data[ix] : 0;
        tot += v[i];
    }
    sd[tid] = tot;
    __syncthreads();
    for (int s = 1; s < 256; s <<= 1){
        int t = (tid >= s) ? sd[tid - s] : 0;
        __syncthreads();
        sd[tid] += t;
        __syncthreads();
    }
    int incl = sd[tid];
    int excl = incl - tot;
    if (tid == 255 && bsums) bsums[blockIdx.x] = incl;
    int run = excl;
    #pragma unroll
    for (int i = 0; i < 8; ++i){
        long ix = base + i;
        if (ix < n) data[ix] = run;
        run += v[i];
    }
}

__global__ void scan_add(int* __restrict__ data, const int* __restrict__ bsums, int n){
    long i = (long)blockIdx.x * 256 + threadIdx.x;
    if (i < n) data[i] += bsums[i >> 11];
}

__global__ void fill_kernel(EdgePtrs ep, RelMeta rm, int* __restrict__ off, int* __restrict__ csr){
    int rel = blockIdx.y;
    int e = blockIdx.x * 256 + threadIdx.x;
    if (e >= EDG) return;
    int src = ep.e[rel][e];
    int dst = ep.e[rel][EDG + e];
    int pos = atomicAdd(&off[rm.base[rel] + dst], 1);
    csr[pos] = src;
}
// NOTE: after fill, off[gr] holds the END of row gr's slot range; start = off[gr-1] (0 for gr==0).

// ---------------- aggregation: sum of per-relation means (<=2 rels), bf16 out ----------------
template<bool SRC32>
__global__ void agg_kernel(const int* __restrict__ off, const int* __restrict__ csr,
                           const void* __restrict__ src0, const void* __restrict__ src1,
                           int relBase0, int relBase1, int nRels, int nRows,
                           u32* __restrict__ mean){
    long g = (long)blockIdx.x * 256 + threadIdx.x;
    int row  = (int)(g >> 6);
    int lane = (int)(g & 63);
    if (row >= nRows) return;
    float a0 = 0.f, a1 = 0.f;
    for (int r = 0; r < nRels; ++r){
        const void* sp = r ? src1 : src0;
        int base = r ? relBase1 : relBase0;
        long gr = (long)base + row;
        int start = (gr == 0) ? 0 : off[gr - 1];
        int end = off[gr];
        float s0 = 0.f, s1 = 0.f;
        for (int j = start; j < end; ++j){
            long s = csr[j];
            if (SRC32){
                const float2 v = *((const float2*)((const float*)sp + s*128 + lane*2));
                s0 += v.x; s1 += v.y;
            } else {
                u32 v = *((const u32*)((const u16*)sp + s*128 + lane*2));
                s0 += b2f((u16)(v & 0xffff));
                s1 += b2f((u16)(v >> 16));
            }
        }
        if (end > start){
            float inv = 1.f / (float)(end - start);
            a0 += s0 * inv; a1 += s1 * inv;
        }
    }
    u32 packed = (u32)f2b(a0) | ((u32)f2b(a1) << 16);
    mean[(long)row * 64 + lane] = packed;
}

// ---------------- MFMA GEMM: C[nRows,128] (+)= A[nRows,128] @ W[128,128] ----------------
// WT is W transposed ([n][k], bf16). A/B k-fragment uses contiguous map k=8*(lane>>4)+j:
// any bijective k-map applied consistently to BOTH operands yields the correct dot product.
template<bool A32, bool ACC>
__global__ __launch_bounds__(256) void gemm_kernel(const void* __restrict__ Ap,
                                                   const u16* __restrict__ WT,
                                                   float* __restrict__ Cp, int nRows){
    __shared__ u16 wl[16384]; // 32KB, XOR-swizzled
    int tid = threadIdx.x;
    #pragma unroll
    for (int c = 0; c < 8; ++c){
        int i = c * 2048 + tid * 8;      // element index; row n = i>>7
        int n = i >> 7;
        int boff = (i * 2) ^ ((n & 7) << 4);
        *(uint4*)((char*)wl + boff) = *(const uint4*)((const char*)WT + (long)i * 2);
    }
    __syncthreads();
    int wave = tid >> 6, lane = tid & 63;
    int row0 = blockIdx.x * 64 + wave * 16;
    if (row0 >= nRows) return;
    int rlo = lane & 15, blk = lane >> 4;

    bf16x8 af[4];
    long arow = (long)row0 + rlo;
    if (A32){
        const float* A = (const float*)Ap + arow * 128;
        #pragma unroll
        for (int s = 0; s < 4; ++s){
            int k0 = s * 32 + blk * 8;
            bf16x8 t;
            #pragma unroll
            for (int j = 0; j < 8; ++j) t[j] = (short)f2b(A[k0 + j]);
            af[s] = t;
        }
    } else {
        const u16* A = (const u16*)Ap + arow * 128;
        #pragma unroll
        for (int s = 0; s < 4; ++s)
            af[s] = *(const bf16x8*)(A + s * 32 + blk * 8);
    }

    f32x4 acc[8];
    #pragma unroll
    for (int nt = 0; nt < 8; ++nt) acc[nt] = (f32x4){0.f, 0.f, 0.f, 0.f};

    #pragma unroll
    for (int s = 0; s < 4; ++s){
        #pragma unroll
        for (int nt = 0; nt < 8; ++nt){
            int n = nt * 16 + rlo;
            int boff = (n * 256 + s * 64 + blk * 16) ^ ((n & 7) << 4);
            bf16x8 bfr = *(const bf16x8*)((const char*)wl + boff);
            acc[nt] = __builtin_amdgcn_mfma_f32_16x16x32_bf16(af[s], bfr, acc[nt], 0, 0, 0);
        }
    }

    long rbase = row0 + blk * 4;
    #pragma unroll
    for (int nt = 0; nt < 8; ++nt){
        int cx = nt * 16 + rlo;
        #pragma unroll
        for (int j = 0; j < 4; ++j){
            long o = (rbase + j) * 128 + cx;
            if (ACC) Cp[o] += acc[nt][j];
            else     Cp[o]  = acc[nt][j];
        }
    }
}

// ---------------- finalize: relu((acc + blSum)/R); layer0 -> bf16 h1, layer1 -> fp32 in place ---
template<int FINAL>
__global__ void finalize_kernel(float* __restrict__ acc, const float* __restrict__ blS,
                                u16* __restrict__ h1){
    long idx = ((long)blockIdx.x * 256 + threadIdx.x) * 4;
    if (idx >= (long)NTOT * 128) return;
    long row = idx >> 7;
    int col = (int)(idx & 127);
    int t = (row < NFILE) ? 0 : (row < (NFILE + NCLASS)) ? 1 : 2;
    float invR = (t == 0) ? 1.f : (t == 1) ? 0.2f : (1.f / 7.f);
    float4 a = *(float4*)(acc + idx);
    const float* bp = blS + t * 128 + col;
    float v0 = fmaxf(0.f, (a.x + bp[0]) * invR);
    float v1 = fmaxf(0.f, (a.y + bp[1]) * invR);
    float v2 = fmaxf(0.f, (a.z + bp[2]) * invR);
    float v3 = fmaxf(0.f, (a.w + bp[3]) * invR);
    if (FINAL){
        float4 o = {v0, v1, v2, v3};
        *(float4*)(acc + idx) = o;
    } else {
        uint2 o;
        o.x = (u32)f2b(v0) | ((u32)f2b(v1) << 16);
        o.y = (u32)f2b(v2) | ((u32)f2b(v3) << 16);
        *(uint2*)(h1 + idx) = o;
    }
}

// ---------------- host ----------------
extern "C" void kernel_launch(void* const* d_in, const int* in_sizes, int n_in,
                              void* d_out, int out_size, void* d_ws, size_t ws_size,
                              hipStream_t stream){
    const float* xF  = (const float*)d_in[0];
    const float* xC  = (const float*)d_in[1];
    const float* xFn = (const float*)d_in[2];
    const float* Wl  = (const float*)d_in[3];
    const float* bl  = (const float*)d_in[4];
    const float* Wr  = (const float*)d_in[5];

    // relation metadata (index in d_in order 6..18)
    static const int relDstT[NRELS] = {1,2,2,0,1,2,1,2,1,2,2,1,2};
    static const int relSrcT[NRELS] = {0,0,0,0,0,0,1,1,2,2,1,1,2};
    const int nOf[3] = {NFILE, NCLASS, NFUNC};

    EdgePtrs ep;
    for (int r = 0; r < NRELS; ++r) ep.e[r] = (const int*)d_in[6 + r];
    RelMeta rm;
    {
        int a = 0;
        for (int r = 0; r < NRELS; ++r){ rm.base[r] = a; a += nOf[relDstT[r]]; }
    }

    // workspace layout (~233MB)
    char* ws = (char*)d_ws;
    size_t wo = 0;
    auto walloc = [&](size_t bytes) -> void* {
        void* p = ws + wo;
        wo = (wo + bytes + 255) & ~(size_t)255;
        return p;
    };
    int* off    = (int*)walloc((size_t)RTOT * 4);
    int* bsums  = (int*)walloc(8192);
    int* csr    = (int*)walloc((size_t)NRELS * EDG * 4);
    u32* mean   = (u32*)walloc((size_t)NFUNC * 64 * 4);
    u16* h1     = (u16*)walloc((size_t)NTOT * 128 * 2);
    u16* WlT    = (u16*)walloc(2 * 4 * 16384 * 2);
    u16* WrSumT = (u16*)walloc(2 * 3 * 16384 * 2);
    float* blSum= (float*)walloc(2 * 3 * 128 * 4);

    prep_weights<<<128, 256, 0, stream>>>(Wl, bl, Wr, WlT, WrSumT, blSum);

    // CSR build (edges identical for both layers)
    hipMemsetAsync(off, 0, (size_t)RTOT * 4, stream);
    dim3 egrid((EDG + 255) / 256, NRELS);
    count_kernel<<<egrid, 256, 0, stream>>>(ep, rm, off);
    int nb1 = (RTOT + 2047) / 2048;
    scan1<<<nb1, 256, 0, stream>>>(off, bsums, RTOT);
    scan1<<<1, 256, 0, stream>>>(bsums, (int*)nullptr, nb1);
    scan_add<<<(RTOT + 255) / 256, 256, 0, stream>>>(off, bsums, RTOT);
    fill_kernel<<<egrid, 256, 0, stream>>>(ep, rm, off, csr);

    float* outSeg[3] = {
        (float*)d_out,
        (float*)d_out + (long)NFILE * 128,
        (float*)d_out + (long)(NFILE + NCLASS) * 128
    };
    u16* hSeg[3] = {
        h1,
        h1 + (long)NFILE * 128,
        h1 + (long)(NFILE + NCLASS) * 128
    };
    const void* xSeg[3] = {xF, xC, xFn};

    // groups: (dstT, ci, nRels, rel0, rel1)
    struct GD { int t, ci, nRels, r0, r1; };
    static const GD gds[9] = {
        {0,1,1, 3,-1},
        {1,0,1, 0,-1}, {1,1,1, 4,-1}, {1,2,2, 6, 8}, {1,3,1,11,-1},
        {2,0,1, 1,-1}, {2,1,2, 2, 5}, {2,2,2, 7, 9}, {2,3,2,10,12},
    };

    for (int layer = 0; layer < 2; ++layer){
        bool l0 = (layer == 0);
        // self term: acc = x @ WrSum  (initializes d_out accumulator)
        for (int t = 0; t < 3; ++t){
            int n = nOf[t];
            int gb = (n + 63) / 64;
            const u16* w = WrSumT + (layer * 3 + t) * 16384;
            if (l0) gemm_kernel<true , false><<<gb, 256, 0, stream>>>(xSeg[t], w, outSeg[t], n);
            else    gemm_kernel<false, false><<<gb, 256, 0, stream>>>(hSeg[t], w, outSeg[t], n);
        }
        // neighbor terms: acc += (sum of relation means) @ Wl[ci]
        for (int g = 0; g < 9; ++g){
            const GD gd = gds[g];
            int n = nOf[gd.t];
            const void* s0 = l0 ? xSeg[relSrcT[gd.r0]] : (const void*)hSeg[relSrcT[gd.r0]];
            const void* s1 = nullptr;
            int b1 = 0;
            if (gd.nRels > 1){
                s1 = l0 ? xSeg[relSrcT[gd.r1]] : (const void*)hSeg[relSrcT[gd.r1]];
                b1 = rm.base[gd.r1];
            }
            int ab = (n + 3) / 4; // one 64-lane wave per dst row
            if (l0) agg_kernel<true ><<<ab, 256, 0, stream>>>(off, csr, s0, s1, rm.base[gd.r0], b1, gd.nRels, n, mean);
            else    agg_kernel<false><<<ab, 256, 0, stream>>>(off, csr, s0, s1, rm.base[gd.r0], b1, gd.nRels, n, mean);
            const u16* w = WlT + (layer * 4 + gd.ci) * 16384;
            int gb = (n + 63) / 64;
            gemm_kernel<false, true><<<gb, 256, 0, stream>>>(mean, w, outSeg[gd.t], n);
        }
        // finalize: relu((acc + biasSum)/R)
        long tot4 = (long)NTOT * 128 / 4;
        int fb = (int)((tot4 + 255) / 256);
        if (l0) finalize_kernel<0><<<fb, 256, 0, stream>>>((float*)d_out, blSum, h1);
        else    finalize_kernel<1><<<fb, 256, 0, stream>>>((float*)d_out, blSum + 3 * 128, (u16*)nullptr);
    }
}

// Round 3
// 2909.238 us; speedup vs baseline: 1.2360x; 1.2360x over previous
//
#include <hip/hip_runtime.h>
#include <hip/hip_bf16.h>
#include <stdint.h>

typedef unsigned short u16;
typedef unsigned int u32;

#define NFILE 50000
#define NCLASS 150000
#define NFUNC 300000
#define NTOT 500000
#define EDG 300000
#define NRELS 13
#define RTOT 2900000

typedef __attribute__((ext_vector_type(8))) short bf16x8;
typedef __attribute__((ext_vector_type(4))) float f32x4;

__device__ __forceinline__ u16 f2b(float v){
    u32 u = __float_as_uint(v);
    u += 0x7fffu + ((u >> 16) & 1u);
    return (u16)(u >> 16);
}
__device__ __forceinline__ float b2f(u16 b){
    return __uint_as_float(((u32)b) << 16);
}
__device__ __forceinline__ u32 pack2(float a, float b){
    return (u32)f2b(a) | ((u32)f2b(b) << 16);
}

struct EdgePtrs { const int* e[NRELS]; };
struct RelMeta  { int base[NRELS]; };

// ---------------- weight prep: transpose + bf16 + Wr/bias sums ----------------
__global__ void prep_weights(const float* __restrict__ Wl, const float* __restrict__ bl,
                             const float* __restrict__ Wr,
                             u16* __restrict__ WlT, u16* __restrict__ WrSumT,
                             float* __restrict__ blSum){
    int tid = blockIdx.x * 256 + threadIdx.x;
    if (tid >= 2 * 16384) return;
    int l   = tid >> 14;
    int rem = tid & 16383;
    int n   = rem >> 7;
    int k   = rem & 127;
    const int m[3][4] = {{0,1,0,0},{1,1,2,1},{1,2,2,2}};
    #pragma unroll
    for (int ci = 0; ci < 4; ++ci){
        float w = Wl[(((l*4)+ci)*128 + k)*128 + n];
        WlT[((l*4+ci)*128 + n)*128 + k] = f2b(w);
    }
    #pragma unroll
    for (int t = 0; t < 3; ++t){
        float s = 0.f;
        #pragma unroll
        for (int ci = 0; ci < 4; ++ci)
            s += (float)m[t][ci] * Wr[(((l*4)+ci)*128 + k)*128 + n];
        WrSumT[((l*3+t)*128 + n)*128 + k] = f2b(s);
    }
    if (k == 0){
        #pragma unroll
        for (int t = 0; t < 3; ++t){
            float s = 0.f;
            #pragma unroll
            for (int ci = 0; ci < 4; ++ci)
                s += (float)m[t][ci] * bl[(l*4+ci)*128 + n];
            blSum[(l*3+t)*128 + n] = s;
        }
    }
}

// ---------------- CSR build ----------------
__global__ void count_kernel(EdgePtrs ep, RelMeta rm, int* __restrict__ off){
    int rel = blockIdx.y;
    int e = blockIdx.x * 256 + threadIdx.x;
    if (e >= EDG) return;
    int dst = ep.e[rel][EDG + e];
    atomicAdd(&off[rm.base[rel] + dst], 1);
}

__global__ void scan1(int* __restrict__ data, int* __restrict__ bsums, int n){
    __shared__ int sd[256];
    int tid = threadIdx.x;
    long base = (long)blockIdx.x * 2048 + (long)tid * 8;
    int v[8]; int tot = 0;
    #pragma unroll
    for (int i = 0; i < 8; ++i){
        long ix = base + i;
        v[i] = (ix < n) ? data[ix] : 0;
        tot += v[i];
    }
    sd[tid] = tot;
    __syncthreads();
    for (int s = 1; s < 256; s <<= 1){
        int t = (tid >= s) ? sd[tid - s] : 0;
        __syncthreads();
        sd[tid] += t;
        __syncthreads();
    }
    int incl = sd[tid];
    int excl = incl - tot;
    if (tid == 255 && bsums) bsums[blockIdx.x] = incl;
    int run = excl;
    #pragma unroll
    for (int i = 0; i < 8; ++i){
        long ix = base + i;
        if (ix < n) data[ix] = run;
        run += v[i];
    }
}

__global__ void scan_add(int* __restrict__ data, const int* __restrict__ bsums, int n){
    long i = (long)blockIdx.x * 256 + threadIdx.x;
    if (i < n) data[i] += bsums[i >> 11];
}

__global__ void fill_kernel(EdgePtrs ep, RelMeta rm, int* __restrict__ off, int* __restrict__ csr){
    int rel = blockIdx.y;
    int e = blockIdx.x * 256 + threadIdx.x;
    if (e >= EDG) return;
    int src = ep.e[rel][e];
    int dst = ep.e[rel][EDG + e];
    int pos = atomicAdd(&off[rm.base[rel] + dst], 1);
    csr[pos] = src;
}
// After fill: off[gr] = END of row gr; start = off[gr-1] (0 for gr==0).

// ---------------- fused per-dst-type layer kernel ----------------
// Block = 64 dst rows, 4 waves (each wave owns 16 rows).
// For each group: aggregate relation-means into LDS (bf16, swizzled),
// stage Wl in LDS (swizzled), MFMA-accumulate. Then self term (A from global),
// then epilogue bias + (1/R) + ReLU, write once (bf16 for layer0, fp32 final).
struct FusedArgs {
    const void* sp0[4];
    const void* sp1[4];
    int b0[4], b1[4], nR[4];
    const u16* wl[4];
    int nG;
    const u16* wself;
    const float* bias;
};

template<bool SRC32, bool FINAL>
__global__ __launch_bounds__(256) void fused_kernel(
    const int* __restrict__ off, const int* __restrict__ csr,
    FusedArgs fa, const void* __restrict__ xdst,
    void* __restrict__ outp, int nRows, float invR)
{
    __shared__ u16 wlds[16384];   // 32KB, swizzled
    __shared__ u16 meanB[8192];   // 16KB, swizzled; 64 rows x 128 cols bf16
    int tid = threadIdx.x, wave = tid >> 6, lane = tid & 63;
    int row0 = blockIdx.x * 64;
    int rlo = lane & 15, blk = lane >> 4;

    f32x4 acc[8];
    #pragma unroll
    for (int nt = 0; nt < 8; ++nt) acc[nt] = (f32x4){0.f, 0.f, 0.f, 0.f};

    for (int g = 0; g < fa.nG; ++g){
        __syncthreads();  // prior MFMA reads of wlds/meanB done
        // stage Wl[g]
        {
            const u16* WT = fa.wl[g];
            #pragma unroll
            for (int c = 0; c < 8; ++c){
                int i = c * 2048 + tid * 8;
                int n = i >> 7;
                int boff = (i * 2) ^ ((n & 7) << 4);
                *(uint4*)((char*)wlds + boff) = *(const uint4*)((const char*)WT + (long)i * 2);
            }
        }
        // aggregate: 4 rows concurrently per wave (16 lanes per row, 8 cols/lane)
        for (int rr = 0; rr < 4; ++rr){
            int row = wave * 16 + rr * 4 + blk;
            long grow = (long)row0 + row;
            bool valid = grow < nRows;
            float a[8];
            #pragma unroll
            for (int k = 0; k < 8; ++k) a[k] = 0.f;
            for (int r = 0; r < fa.nR[g]; ++r){
                const void* sp = r ? fa.sp1[g] : fa.sp0[g];
                long gr = (long)(r ? fa.b1[g] : fa.b0[g]) + grow;
                int st = 0, en = 0;
                if (valid){ st = (gr > 0) ? off[gr - 1] : 0; en = off[gr]; }
                float s[8], s2[8];
                #pragma unroll
                for (int k = 0; k < 8; ++k){ s[k] = 0.f; s2[k] = 0.f; }
                int j = st;
                for (; j + 1 < en; j += 2){
                    long i0 = csr[j], i1 = csr[j + 1];
                    if (SRC32){
                        const float* p0 = (const float*)sp + i0 * 128 + rlo * 8;
                        const float* p1 = (const float*)sp + i1 * 128 + rlo * 8;
                        float4 u0 = *(const float4*)p0, u1 = *(const float4*)(p0 + 4);
                        float4 v0 = *(const float4*)p1, v1 = *(const float4*)(p1 + 4);
                        s[0] += u0.x; s[1] += u0.y; s[2] += u0.z; s[3] += u0.w;
                        s[4] += u1.x; s[5] += u1.y; s[6] += u1.z; s[7] += u1.w;
                        s2[0] += v0.x; s2[1] += v0.y; s2[2] += v0.z; s2[3] += v0.w;
                        s2[4] += v1.x; s2[5] += v1.y; s2[6] += v1.z; s2[7] += v1.w;
                    } else {
                        uint4 u = *(const uint4*)((const u16*)sp + i0 * 128 + rlo * 8);
                        uint4 v = *(const uint4*)((const u16*)sp + i1 * 128 + rlo * 8);
                        s[0] += b2f((u16)(u.x & 0xffff)); s[1] += b2f((u16)(u.x >> 16));
                        s[2] += b2f((u16)(u.y & 0xffff)); s[3] += b2f((u16)(u.y >> 16));
                        s[4] += b2f((u16)(u.z & 0xffff)); s[5] += b2f((u16)(u.z >> 16));
                        s[6] += b2f((u16)(u.w & 0xffff)); s[7] += b2f((u16)(u.w >> 16));
                        s2[0] += b2f((u16)(v.x & 0xffff)); s2[1] += b2f((u16)(v.x >> 16));
                        s2[2] += b2f((u16)(v.y & 0xffff)); s2[3] += b2f((u16)(v.y >> 16));
                        s2[4] += b2f((u16)(v.z & 0xffff)); s2[5] += b2f((u16)(v.z >> 16));
                        s2[6] += b2f((u16)(v.w & 0xffff)); s2[7] += b2f((u16)(v.w >> 16));
                    }
                }
                if (j < en){
                    long i0 = csr[j];
                    if (SRC32){
                        const float* p0 = (const float*)sp + i0 * 128 + rlo * 8;
                        float4 u0 = *(const float4*)p0, u1 = *(const float4*)(p0 + 4);
                        s[0] += u0.x; s[1] += u0.y; s[2] += u0.z; s[3] += u0.w;
                        s[4] += u1.x; s[5] += u1.y; s[6] += u1.z; s[7] += u1.w;
                    } else {
                        uint4 u = *(const uint4*)((const u16*)sp + i0 * 128 + rlo * 8);
                        s[0] += b2f((u16)(u.x & 0xffff)); s[1] += b2f((u16)(u.x >> 16));
                        s[2] += b2f((u16)(u.y & 0xffff)); s[3] += b2f((u16)(u.y >> 16));
                        s[4] += b2f((u16)(u.z & 0xffff)); s[5] += b2f((u16)(u.z >> 16));
                        s[6] += b2f((u16)(u.w & 0xffff)); s[7] += b2f((u16)(u.w >> 16));
                    }
                }
                if (en > st){
                    float inv = 1.f / (float)(en - st);
                    #pragma unroll
                    for (int k = 0; k < 8; ++k) a[k] += (s[k] + s2[k]) * inv;
                }
            }
            uint4 w;
            w.x = pack2(a[0], a[1]); w.y = pack2(a[2], a[3]);
            w.z = pack2(a[4], a[5]); w.w = pack2(a[6], a[7]);
            int boff = (row * 256 + rlo * 16) ^ ((row & 7) << 4);
            *(uint4*)((char*)meanB + boff) = w;
        }
        __syncthreads();
        // MFMA accumulate
        int arow = wave * 16 + rlo;
        #pragma unroll
        for (int s4 = 0; s4 < 4; ++s4){
            int aoff = (arow * 256 + s4 * 64 + blk * 16) ^ ((arow & 7) << 4);
            bf16x8 afr = *(const bf16x8*)((const char*)meanB + aoff);
            #pragma unroll
            for (int nt = 0; nt < 8; ++nt){
                int n = nt * 16 + rlo;
                int boff = (n * 256 + s4 * 64 + blk * 16) ^ ((n & 7) << 4);
                bf16x8 bfr = *(const bf16x8*)((const char*)wlds + boff);
                acc[nt] = __builtin_amdgcn_mfma_f32_16x16x32_bf16(afr, bfr, acc[nt], 0, 0, 0);
            }
        }
    }

    // self term: A from global (contiguous rows)
    __syncthreads();
    {
        const u16* WT = fa.wself;
        #pragma unroll
        for (int c = 0; c < 8; ++c){
            int i = c * 2048 + tid * 8;
            int n = i >> 7;
            int boff = (i * 2) ^ ((n & 7) << 4);
            *(uint4*)((char*)wlds + boff) = *(const uint4*)((const char*)WT + (long)i * 2);
        }
    }
    __syncthreads();
    {
        long arow = (long)row0 + wave * 16 + rlo;
        if (arow >= nRows) arow = nRows - 1;
        bf16x8 af[4];
        if (SRC32){
            const float* A = (const float*)xdst + arow * 128;
            #pragma unroll
            for (int s4 = 0; s4 < 4; ++s4){
                float4 u0 = *(const float4*)(A + s4 * 32 + blk * 8);
                float4 u1 = *(const float4*)(A + s4 * 32 + blk * 8 + 4);
                bf16x8 t;
                t[0] = (short)f2b(u0.x); t[1] = (short)f2b(u0.y);
                t[2] = (short)f2b(u0.z); t[3] = (short)f2b(u0.w);
                t[4] = (short)f2b(u1.x); t[5] = (short)f2b(u1.y);
                t[6] = (short)f2b(u1.z); t[7] = (short)f2b(u1.w);
                af[s4] = t;
            }
        } else {
            const u16* A = (const u16*)xdst + arow * 128;
            #pragma unroll
            for (int s4 = 0; s4 < 4; ++s4)
                af[s4] = *(const bf16x8*)(A + s4 * 32 + blk * 8);
        }
        #pragma unroll
        for (int s4 = 0; s4 < 4; ++s4){
            #pragma unroll
            for (int nt = 0; nt < 8; ++nt){
                int n = nt * 16 + rlo;
                int boff = (n * 256 + s4 * 64 + blk * 16) ^ ((n & 7) << 4);
                bf16x8 bfr = *(const bf16x8*)((const char*)wlds + boff);
                acc[nt] = __builtin_amdgcn_mfma_f32_16x16x32_bf16(af[s4], bfr, acc[nt], 0, 0, 0);
            }
        }
    }

    // epilogue: relu((acc + bias) * invR), single write
    long rb = (long)row0 + wave * 16 + blk * 4;
    #pragma unroll
    for (int nt = 0; nt < 8; ++nt){
        int cx = nt * 16 + rlo;
        float b = fa.bias[cx];
        #pragma unroll
        for (int j = 0; j < 4; ++j){
            long r = rb + j;
            if (r < nRows){
                float v = fmaxf(0.f, (acc[nt][j] + b) * invR);
                if (FINAL) ((float*)outp)[r * 128 + cx] = v;
                else       ((u16*)outp)[r * 128 + cx] = f2b(v);
            }
        }
    }
}

// ---------------- host ----------------
extern "C" void kernel_launch(void* const* d_in, const int* in_sizes, int n_in,
                              void* d_out, int out_size, void* d_ws, size_t ws_size,
                              hipStream_t stream){
    const float* xF  = (const float*)d_in[0];
    const float* xC  = (const float*)d_in[1];
    const float* xFn = (const float*)d_in[2];
    const float* Wl  = (const float*)d_in[3];
    const float* bl  = (const float*)d_in[4];
    const float* Wr  = (const float*)d_in[5];

    static const int relDstT[NRELS] = {1,2,2,0,1,2,1,2,1,2,2,1,2};
    static const int relSrcT[NRELS] = {0,0,0,0,0,0,1,1,2,2,1,1,2};
    const int nOf[3] = {NFILE, NCLASS, NFUNC};

    EdgePtrs ep;
    for (int r = 0; r < NRELS; ++r) ep.e[r] = (const int*)d_in[6 + r];
    RelMeta rm;
    {
        int a = 0;
        for (int r = 0; r < NRELS; ++r){ rm.base[r] = a; a += nOf[relDstT[r]]; }
    }

    // workspace (~156MB)
    char* ws = (char*)d_ws;
    size_t wo = 0;
    auto walloc = [&](size_t bytes) -> void* {
        void* p = ws + wo;
        wo = (wo + bytes + 255) & ~(size_t)255;
        return p;
    };
    int* off    = (int*)walloc((size_t)RTOT * 4);
    int* bsums  = (int*)walloc(8192);
    int* csr    = (int*)walloc((size_t)NRELS * EDG * 4);
    u16* h1     = (u16*)walloc((size_t)NTOT * 128 * 2);
    u16* WlT    = (u16*)walloc(2 * 4 * 16384 * 2);
    u16* WrSumT = (u16*)walloc(2 * 3 * 16384 * 2);
    float* blSum= (float*)walloc(2 * 3 * 128 * 4);

    prep_weights<<<128, 256, 0, stream>>>(Wl, bl, Wr, WlT, WrSumT, blSum);

    hipMemsetAsync(off, 0, (size_t)RTOT * 4, stream);
    dim3 egrid((EDG + 255) / 256, NRELS);
    count_kernel<<<egrid, 256, 0, stream>>>(ep, rm, off);
    int nb1 = (RTOT + 2047) / 2048;
    scan1<<<nb1, 256, 0, stream>>>(off, bsums, RTOT);
    scan1<<<1, 256, 0, stream>>>(bsums, (int*)nullptr, nb1);
    scan_add<<<(RTOT + 255) / 256, 256, 0, stream>>>(off, bsums, RTOT);
    fill_kernel<<<egrid, 256, 0, stream>>>(ep, rm, off, csr);

    float* outSeg[3] = {
        (float*)d_out,
        (float*)d_out + (long)NFILE * 128,
        (float*)d_out + (long)(NFILE + NCLASS) * 128
    };
    u16* hSeg[3] = {
        h1,
        h1 + (long)NFILE * 128,
        h1 + (long)(NFILE + NCLASS) * 128
    };
    const void* xSeg[3] = {xF, xC, xFn};
    const float invR[3] = {1.f, 0.2f, 1.f / 7.f};

    // groups per dst type: list of (ci, rel0, rel1)
    struct GDef { int ci, r0, r1; };
    static const GDef gF [1] = {{1, 3, -1}};
    static const GDef gC [4] = {{0, 0, -1}, {1, 4, -1}, {2, 6, 8}, {3, 11, -1}};
    static const GDef gFn[4] = {{0, 1, -1}, {1, 2, 5}, {2, 7, 9}, {3, 10, 12}};
    const GDef* gdefs[3] = {gF, gC, gFn};
    const int nGof[3] = {1, 4, 4};

    for (int layer = 0; layer < 2; ++layer){
        bool l0 = (layer == 0);
        for (int t = 0; t < 3; ++t){
            FusedArgs fa;
            fa.nG = nGof[t];
            for (int g = 0; g < fa.nG; ++g){
                const GDef gd = gdefs[t][g];
                fa.wl[g] = WlT + (layer * 4 + gd.ci) * 16384;
                fa.b0[g] = rm.base[gd.r0];
                fa.sp0[g] = l0 ? xSeg[relSrcT[gd.r0]] : (const void*)hSeg[relSrcT[gd.r0]];
                if (gd.r1 >= 0){
                    fa.nR[g] = 2;
                    fa.b1[g] = rm.base[gd.r1];
                    fa.sp1[g] = l0 ? xSeg[relSrcT[gd.r1]] : (const void*)hSeg[relSrcT[gd.r1]];
                } else {
                    fa.nR[g] = 1;
                    fa.b1[g] = 0;
                    fa.sp1[g] = nullptr;
                }
            }
            for (int g = fa.nG; g < 4; ++g){
                fa.wl[g] = nullptr; fa.b0[g] = fa.b1[g] = fa.nR[g] = 0;
                fa.sp0[g] = fa.sp1[g] = nullptr;
            }
            fa.wself = WrSumT + (layer * 3 + t) * 16384;
            fa.bias  = blSum + (layer * 3 + t) * 128;

            int n = nOf[t];
            int gb = (n + 63) / 64;
            const void* xdst = l0 ? xSeg[t] : (const void*)hSeg[t];
            void* outp = l0 ? (void*)hSeg[t] : (void*)outSeg[t];
            if (l0) fused_kernel<true , false><<<gb, 256, 0, stream>>>(off, csr, fa, xdst, outp, n, invR[t]);
            else    fused_kernel<false, true ><<<gb, 256, 0, stream>>>(off, csr, fa, xdst, outp, n, invR[t]);
        }
    }
}

// Round 4
// 2806.765 us; speedup vs baseline: 1.2811x; 1.0365x over previous
//
#include <hip/hip_runtime.h>
#include <hip/hip_bf16.h>
#include <stdint.h>

typedef unsigned short u16;
typedef unsigned int u32;

#define NFILE 50000
#define NCLASS 150000
#define NFUNC 300000
#define NTOT 500000
#define EDG 300000
#define NRELS 13
#define RTOT 2900000
#define CSRMAX (NRELS * EDG)

typedef __attribute__((ext_vector_type(8))) short bf16x8;
typedef __attribute__((ext_vector_type(4))) float f32x4;

__device__ __forceinline__ u16 f2b(float v){
    u32 u = __float_as_uint(v);
    u += 0x7fffu + ((u >> 16) & 1u);
    return (u16)(u >> 16);
}
__device__ __forceinline__ float b2f(u16 b){
    return __uint_as_float(((u32)b) << 16);
}
__device__ __forceinline__ u32 pack2(float a, float b){
    return (u32)f2b(a) | ((u32)f2b(b) << 16);
}

struct EdgePtrs { const int* e[NRELS]; };
struct RelMeta  { int base[NRELS]; };

// ---------------- weight prep ----------------
__global__ void prep_weights(const float* __restrict__ Wl, const float* __restrict__ bl,
                             const float* __restrict__ Wr,
                             u16* __restrict__ WlT, u16* __restrict__ WrSumT,
                             float* __restrict__ blSum){
    int tid = blockIdx.x * 256 + threadIdx.x;
    if (tid >= 2 * 16384) return;
    int l   = tid >> 14;
    int rem = tid & 16383;
    int n   = rem >> 7;
    int k   = rem & 127;
    const int m[3][4] = {{0,1,0,0},{1,1,2,1},{1,2,2,2}};
    #pragma unroll
    for (int ci = 0; ci < 4; ++ci){
        float w = Wl[(((l*4)+ci)*128 + k)*128 + n];
        WlT[((l*4+ci)*128 + n)*128 + k] = f2b(w);
    }
    #pragma unroll
    for (int t = 0; t < 3; ++t){
        float s = 0.f;
        #pragma unroll
        for (int ci = 0; ci < 4; ++ci)
            s += (float)m[t][ci] * Wr[(((l*4)+ci)*128 + k)*128 + n];
        WrSumT[((l*3+t)*128 + n)*128 + k] = f2b(s);
    }
    if (k == 0){
        #pragma unroll
        for (int t = 0; t < 3; ++t){
            float s = 0.f;
            #pragma unroll
            for (int ci = 0; ci < 4; ++ci)
                s += (float)m[t][ci] * bl[(l*4+ci)*128 + n];
            blSum[(l*3+t)*128 + n] = s;
        }
    }
}

// ---------------- CSR build ----------------
__global__ void count_kernel(EdgePtrs ep, RelMeta rm, int* __restrict__ off){
    int rel = blockIdx.y;
    int e = blockIdx.x * 256 + threadIdx.x;
    if (e >= EDG) return;
    int dst = ep.e[rel][EDG + e];
    atomicAdd(&off[rm.base[rel] + dst], 1);
}

__global__ void scan1(int* __restrict__ data, int* __restrict__ bsums, int n){
    __shared__ int sd[256];
    int tid = threadIdx.x;
    long base = (long)blockIdx.x * 2048 + (long)tid * 8;
    int v[8]; int tot = 0;
    #pragma unroll
    for (int i = 0; i < 8; ++i){
        long ix = base + i;
        v[i] = (ix < n) ? data[ix] : 0;
        tot += v[i];
    }
    sd[tid] = tot;
    __syncthreads();
    for (int s = 1; s < 256; s <<= 1){
        int t = (tid >= s) ? sd[tid - s] : 0;
        __syncthreads();
        sd[tid] += t;
        __syncthreads();
    }
    int incl = sd[tid];
    int excl = incl - tot;
    if (tid == 255 && bsums) bsums[blockIdx.x] = incl;
    int run = excl;
    #pragma unroll
    for (int i = 0; i < 8; ++i){
        long ix = base + i;
        if (ix < n) data[ix] = run;
        run += v[i];
    }
}

__global__ void scan_add(int* __restrict__ data, const int* __restrict__ bsums, int n){
    long i = (long)blockIdx.x * 256 + threadIdx.x;
    if (i < n) data[i] += bsums[i >> 11];
}

__global__ void fill_kernel(EdgePtrs ep, RelMeta rm, int* __restrict__ off, int* __restrict__ csr){
    int rel = blockIdx.y;
    int e = blockIdx.x * 256 + threadIdx.x;
    if (e >= EDG) return;
    int src = ep.e[rel][e];
    int dst = ep.e[rel][EDG + e];
    int pos = atomicAdd(&off[rm.base[rel] + dst], 1);
    csr[pos] = src;
}
// After fill: off[gr] = END of row gr; start = off[gr-1] (0 for gr==0).

// ---------------- fused v2 ----------------
// Per dst type (templated): block = 64 rows, 4 waves. Phases of 2 groups:
// branchless deg<=2 aggregation with compile-time-unrolled slots (max MLP),
// means -> 2x16KB LDS, MFMA with B-fragments straight from global (L2-hot W).
// Self term barrier-free, epilogue in-register. LDS total 32KB.

template<int T> struct Meta;
template<> struct Meta<0>{ static constexpr int NG=1, NS=1;
    static constexpr int sg[1]={0}; };
template<> struct Meta<1>{ static constexpr int NG=4, NS=5;
    static constexpr int sg[5]={0,1,2,2,3}; };
template<> struct Meta<2>{ static constexpr int NG=4, NS=7;
    static constexpr int sg[7]={0,1,1,2,2,3,3}; };

struct FA2 {
    const void* sp[7];   // per-slot src feature base
    int ob[7];           // per-slot off-array base (row offset into off[])
    int ns[7];           // per-slot #src rows (index clamp)
    const u16* wg[4];    // per-group WlT (128x128 bf16, [n][k])
    const u16* wself;
    const float* bias;
};

template<bool SRC32>
__device__ __forceinline__ void gadd(const void* sp, long idx, int rlo, float w, float a[8]){
    if (SRC32){
        const float* pp = (const float*)sp + idx * 128 + rlo * 8;
        float4 u0 = *(const float4*)pp, u1 = *(const float4*)(pp + 4);
        a[0] += w * u0.x; a[1] += w * u0.y; a[2] += w * u0.z; a[3] += w * u0.w;
        a[4] += w * u1.x; a[5] += w * u1.y; a[6] += w * u1.z; a[7] += w * u1.w;
    } else {
        uint4 u = *(const uint4*)((const u16*)sp + idx * 128 + rlo * 8);
        a[0] += w * b2f((u16)(u.x & 0xffff)); a[1] += w * b2f((u16)(u.x >> 16));
        a[2] += w * b2f((u16)(u.y & 0xffff)); a[3] += w * b2f((u16)(u.y >> 16));
        a[4] += w * b2f((u16)(u.z & 0xffff)); a[5] += w * b2f((u16)(u.z >> 16));
        a[6] += w * b2f((u16)(u.w & 0xffff)); a[7] += w * b2f((u16)(u.w >> 16));
    }
}

template<bool SRC32>
__device__ __forceinline__ void slotAcc(const int* __restrict__ off, const int* __restrict__ csr,
                                        const void* sp, int ob, int ns,
                                        int grow, bool valid, int rlo, float a[8]){
    int st = 0, en = 0;
    if (valid){
        long gr = (long)ob + grow;
        st = (gr > 0) ? off[gr - 1] : 0;
        en = off[gr];
    }
    int deg = en - st;
    float sc = (deg > 0) ? 1.f / (float)deg : 0.f;
    int p0 = min(st, CSRMAX - 1);
    int i0 = csr[p0];
    int i1 = csr[min(p0 + 1, CSRMAX - 1)];
    i0 = min(i0, ns - 1);
    i1 = min(i1, ns - 1);
    float w0 = (deg >= 1) ? sc : 0.f;
    float w1 = (deg >= 2) ? sc : 0.f;
    gadd<SRC32>(sp, i0, rlo, w0, a);
    gadd<SRC32>(sp, i1, rlo, w1, a);
    #pragma unroll 1
    for (int j = st + 2; j < en; ++j){
        int ix = csr[j];
        gadd<SRC32>(sp, ix, rlo, sc, a);
    }
}

__device__ __forceinline__ void mfmaGrp(const u16* mbuf, const u16* __restrict__ W,
                                        f32x4 acc[8], int wave, int rlo, int blk){
    int arow = wave * 16 + rlo;
    #pragma unroll
    for (int s4 = 0; s4 < 4; ++s4){
        int aoff = (arow * 256 + s4 * 64 + blk * 16) ^ ((arow & 7) << 4);
        bf16x8 afr = *(const bf16x8*)((const char*)mbuf + aoff);
        #pragma unroll
        for (int nt = 0; nt < 8; ++nt){
            int n = nt * 16 + rlo;
            bf16x8 bfr = *(const bf16x8*)(W + n * 128 + s4 * 32 + blk * 8);
            acc[nt] = __builtin_amdgcn_mfma_f32_16x16x32_bf16(afr, bfr, acc[nt], 0, 0, 0);
        }
    }
}

template<int T, bool SRC32, bool FINAL>
__global__ __launch_bounds__(256, 4) void fused2(
    const int* __restrict__ off, const int* __restrict__ csr,
    FA2 fa, const void* __restrict__ xdst, void* __restrict__ outp,
    int nRows, float invR)
{
    using M = Meta<T>;
    constexpr int NPH = (M::NG + 1) / 2;
    __shared__ u16 mb[2][8192];   // 2 x 16KB mean buffers, XOR-swizzled
    int tid = threadIdx.x, wave = tid >> 6, lane = tid & 63;
    int row0 = blockIdx.x * 64;
    int rlo = lane & 15, blk = lane >> 4;

    f32x4 acc[8];
    #pragma unroll
    for (int nt = 0; nt < 8; ++nt) acc[nt] = (f32x4){0.f, 0.f, 0.f, 0.f};

    #pragma unroll
    for (int p = 0; p < NPH; ++p){
        bool hasB = (2 * p + 1) < M::NG;   // compile-time folds per unrolled p
        __syncthreads();                    // protect mb reuse from prior MFMA reads
        #pragma unroll 1
        for (int rr = 0; rr < 4; ++rr){
            int row = wave * 16 + rr * 4 + blk;
            int grow = row0 + row;
            bool valid = grow < nRows;
            float aA[8];
            #pragma unroll
            for (int k = 0; k < 8; ++k) aA[k] = 0.f;
            #pragma unroll
            for (int s = 0; s < M::NS; ++s){
                if (M::sg[s] != 2 * p) continue;
                slotAcc<SRC32>(off, csr, fa.sp[s], fa.ob[s], fa.ns[s], grow, valid, rlo, aA);
            }
            {
                uint4 w;
                w.x = pack2(aA[0], aA[1]); w.y = pack2(aA[2], aA[3]);
                w.z = pack2(aA[4], aA[5]); w.w = pack2(aA[6], aA[7]);
                int boff = (row * 256 + rlo * 16) ^ ((row & 7) << 4);
                *(uint4*)((char*)mb[0] + boff) = w;
            }
            if (hasB){
                float aB[8];
                #pragma unroll
                for (int k = 0; k < 8; ++k) aB[k] = 0.f;
                #pragma unroll
                for (int s = 0; s < M::NS; ++s){
                    if (M::sg[s] != 2 * p + 1) continue;
                    slotAcc<SRC32>(off, csr, fa.sp[s], fa.ob[s], fa.ns[s], grow, valid, rlo, aB);
                }
                uint4 w;
                w.x = pack2(aB[0], aB[1]); w.y = pack2(aB[2], aB[3]);
                w.z = pack2(aB[4], aB[5]); w.w = pack2(aB[6], aB[7]);
                int boff = (row * 256 + rlo * 16) ^ ((row & 7) << 4);
                *(uint4*)((char*)mb[1] + boff) = w;
            }
        }
        __syncthreads();
        mfmaGrp(mb[0], fa.wg[2 * p], acc, wave, rlo, blk);
        if (hasB) mfmaGrp(mb[1], fa.wg[2 * p + 1], acc, wave, rlo, blk);
    }

    // self term: A from global rows, B from global wself (no LDS, no barrier)
    {
        long arow = (long)row0 + wave * 16 + rlo;
        if (arow >= nRows) arow = nRows - 1;
        bf16x8 af[4];
        if (SRC32){
            const float* A = (const float*)xdst + arow * 128;
            #pragma unroll
            for (int s4 = 0; s4 < 4; ++s4){
                float4 u0 = *(const float4*)(A + s4 * 32 + blk * 8);
                float4 u1 = *(const float4*)(A + s4 * 32 + blk * 8 + 4);
                bf16x8 t;
                t[0] = (short)f2b(u0.x); t[1] = (short)f2b(u0.y);
                t[2] = (short)f2b(u0.z); t[3] = (short)f2b(u0.w);
                t[4] = (short)f2b(u1.x); t[5] = (short)f2b(u1.y);
                t[6] = (short)f2b(u1.z); t[7] = (short)f2b(u1.w);
                af[s4] = t;
            }
        } else {
            const u16* A = (const u16*)xdst + arow * 128;
            #pragma unroll
            for (int s4 = 0; s4 < 4; ++s4)
                af[s4] = *(const bf16x8*)(A + s4 * 32 + blk * 8);
        }
        #pragma unroll
        for (int s4 = 0; s4 < 4; ++s4){
            #pragma unroll
            for (int nt = 0; nt < 8; ++nt){
                int n = nt * 16 + rlo;
                bf16x8 bfr = *(const bf16x8*)(fa.wself + n * 128 + s4 * 32 + blk * 8);
                acc[nt] = __builtin_amdgcn_mfma_f32_16x16x32_bf16(af[s4], bfr, acc[nt], 0, 0, 0);
            }
        }
    }

    // epilogue: relu((acc + bias) * invR), single write
    long rb = (long)row0 + wave * 16 + blk * 4;
    #pragma unroll
    for (int nt = 0; nt < 8; ++nt){
        int cx = nt * 16 + rlo;
        float b = fa.bias[cx];
        #pragma unroll
        for (int j = 0; j < 4; ++j){
            long r = rb + j;
            if (r < nRows){
                float v = fmaxf(0.f, (acc[nt][j] + b) * invR);
                if (FINAL) ((float*)outp)[r * 128 + cx] = v;
                else       ((u16*)outp)[r * 128 + cx] = f2b(v);
            }
        }
    }
}

// ---------------- host ----------------
extern "C" void kernel_launch(void* const* d_in, const int* in_sizes, int n_in,
                              void* d_out, int out_size, void* d_ws, size_t ws_size,
                              hipStream_t stream){
    const float* xF  = (const float*)d_in[0];
    const float* xC  = (const float*)d_in[1];
    const float* xFn = (const float*)d_in[2];
    const float* Wl  = (const float*)d_in[3];
    const float* bl  = (const float*)d_in[4];
    const float* Wr  = (const float*)d_in[5];

    static const int relDstT[NRELS] = {1,2,2,0,1,2,1,2,1,2,2,1,2};
    static const int relSrcT[NRELS] = {0,0,0,0,0,0,1,1,2,2,1,1,2};
    const int nOf[3] = {NFILE, NCLASS, NFUNC};

    EdgePtrs ep;
    for (int r = 0; r < NRELS; ++r) ep.e[r] = (const int*)d_in[6 + r];
    RelMeta rm;
    {
        int a = 0;
        for (int r = 0; r < NRELS; ++r){ rm.base[r] = a; a += nOf[relDstT[r]]; }
    }

    // workspace (~156MB)
    char* ws = (char*)d_ws;
    size_t wo = 0;
    auto walloc = [&](size_t bytes) -> void* {
        void* p = ws + wo;
        wo = (wo + bytes + 255) & ~(size_t)255;
        return p;
    };
    int* off    = (int*)walloc((size_t)RTOT * 4);
    int* bsums  = (int*)walloc(8192);
    int* csr    = (int*)walloc((size_t)NRELS * EDG * 4);
    u16* h1     = (u16*)walloc((size_t)NTOT * 128 * 2);
    u16* WlT    = (u16*)walloc(2 * 4 * 16384 * 2);
    u16* WrSumT = (u16*)walloc(2 * 3 * 16384 * 2);
    float* blSum= (float*)walloc(2 * 3 * 128 * 4);

    prep_weights<<<128, 256, 0, stream>>>(Wl, bl, Wr, WlT, WrSumT, blSum);

    hipMemsetAsync(off, 0, (size_t)RTOT * 4, stream);
    dim3 egrid((EDG + 255) / 256, NRELS);
    count_kernel<<<egrid, 256, 0, stream>>>(ep, rm, off);
    int nb1 = (RTOT + 2047) / 2048;
    scan1<<<nb1, 256, 0, stream>>>(off, bsums, RTOT);
    scan1<<<1, 256, 0, stream>>>(bsums, (int*)nullptr, nb1);
    scan_add<<<(RTOT + 255) / 256, 256, 0, stream>>>(off, bsums, RTOT);
    fill_kernel<<<egrid, 256, 0, stream>>>(ep, rm, off, csr);

    float* outSeg[3] = {
        (float*)d_out,
        (float*)d_out + (long)NFILE * 128,
        (float*)d_out + (long)(NFILE + NCLASS) * 128
    };
    u16* hSeg[3] = {
        h1,
        h1 + (long)NFILE * 128,
        h1 + (long)(NFILE + NCLASS) * 128
    };
    const void* xSeg[3] = {xF, xC, xFn};
    const float invR[3] = {1.f, 0.2f, 1.f / 7.f};

    // per-type slot tables (relation index per slot) and per-group conv idx
    static const int slotRelF [1] = {3};
    static const int slotRelC [5] = {0, 4, 6, 8, 11};
    static const int slotRelFn[7] = {1, 2, 5, 7, 9, 10, 12};
    const int* slotRelOf[3] = {slotRelF, slotRelC, slotRelFn};
    const int nSlotOf[3] = {1, 5, 7};
    static const int ciF [1] = {1};
    static const int ciC [4] = {0, 1, 2, 3};
    static const int ciFn[4] = {0, 1, 2, 3};
    const int* ciOf[3] = {ciF, ciC, ciFn};
    const int nGof[3] = {1, 4, 4};

    for (int layer = 0; layer < 2; ++layer){
        bool l0 = (layer == 0);
        for (int t = 0; t < 3; ++t){
            FA2 fa;
            for (int s = 0; s < 7; ++s){ fa.sp[s] = nullptr; fa.ob[s] = 0; fa.ns[s] = 1; }
            for (int s = 0; s < nSlotOf[t]; ++s){
                int rel = slotRelOf[t][s];
                int st_ = relSrcT[rel];
                fa.sp[s] = l0 ? xSeg[st_] : (const void*)hSeg[st_];
                fa.ob[s] = rm.base[rel];
                fa.ns[s] = nOf[st_];
            }
            for (int g = 0; g < 4; ++g)
                fa.wg[g] = (g < nGof[t]) ? (WlT + (layer * 4 + ciOf[t][g]) * 16384) : (const u16*)nullptr;
            fa.wself = WrSumT + (layer * 3 + t) * 16384;
            fa.bias  = blSum + (layer * 3 + t) * 128;

            int n = nOf[t];
            int gb = (n + 63) / 64;
            const void* xdst = l0 ? xSeg[t] : (const void*)hSeg[t];
            void* outp = l0 ? (void*)hSeg[t] : (void*)outSeg[t];
            if (l0){
                switch (t){
                    case 0: fused2<0, true, false><<<gb, 256, 0, stream>>>(off, csr, fa, xdst, outp, n, invR[t]); break;
                    case 1: fused2<1, true, false><<<gb, 256, 0, stream>>>(off, csr, fa, xdst, outp, n, invR[t]); break;
                    case 2: fused2<2, true, false><<<gb, 256, 0, stream>>>(off, csr, fa, xdst, outp, n, invR[t]); break;
                }
            } else {
                switch (t){
                    case 0: fused2<0, false, true><<<gb, 256, 0, stream>>>(off, csr, fa, xdst, outp, n, invR[t]); break;
                    case 1: fused2<1, false, true><<<gb, 256, 0, stream>>>(off, csr, fa, xdst, outp, n, invR[t]); break;
                    case 2: fused2<2, false, true><<<gb, 256, 0, stream>>>(off, csr, fa, xdst, outp, n, invR[t]); break;
                }
            }
        }
    }
}